// Round 2
// baseline (446.418 us; speedup 1.0000x reference)
//
#include <hip/hip_runtime.h>

// YOLO post-process: per-level exact top-64 -> concat -> stable sort by score
// -> class-offset greedy NMS. BATCH=128, levels (160x160,s8),(80x80,s16),(40x40,s32).

#define NUM_CLASSES 5
#define CONF_THRESH 0.6f
#define NMS_THRESH  0.2f
#define TOPK   64
#define BATCH  128
#define TOTK   192   // 3 * TOPK

#define CAP    4096                      // LDS candidate buffer entries (u64)
#define TILE   512                       // anchors per tile == blockDim of topk kernel
#define WATERMARK (CAP - TILE*NUM_CLASSES)  // 1536: compact when cnt exceeds this

typedef unsigned long long u64;
typedef unsigned int u32;

#define SEL3(arr, s) ((s) == 0 ? (arr)[0] : ((s) == 1 ? (arr)[1] : (arr)[2]))

// Descending bitonic sort of k[0..m) (m pow2) in LDS, block-cooperative.
// Each (kk,j) pass is a perfect matching (only lower index of a pair swaps);
// barriers are in uniform control flow.
__device__ void bitonic_desc(u64* k, int m) {
  for (int kk = 2; kk <= m; kk <<= 1) {
    for (int j = kk >> 1; j > 0; j >>= 1) {
      __syncthreads();
      for (int i = threadIdx.x; i < m; i += blockDim.x) {
        int ixj = i ^ j;
        if (ixj > i) {
          u64 a = k[i], b = k[ixj];
          bool sw = ((i & kk) == 0) ? (a < b) : (a > b);
          if (sw) { k[i] = b; k[ixj] = a; }
        }
      }
    }
  }
  __syncthreads();
}

// One block per (image, level): exact top-64 of hw*5 scores with
// lax.top_k tie semantics (value desc, index asc) via key = (bits<<32)|~idx.
__global__ __launch_bounds__(TILE) void topk_kernel(
    const float* __restrict__ obj8,  const float* __restrict__ cls8,  const float* __restrict__ reg8,
    const float* __restrict__ obj16, const float* __restrict__ cls16, const float* __restrict__ reg16,
    const float* __restrict__ obj32, const float* __restrict__ cls32, const float* __restrict__ reg32,
    float* __restrict__ ws_score, int* __restrict__ ws_label, float* __restrict__ ws_box) {
  __shared__ u64 keys[CAP];
  __shared__ int cnt;
  __shared__ u64 thrKey;

  const int bx  = blockIdx.x;
  const int lvl = bx / BATCH;          // 0,1,2
  const int img = bx - lvl * BATCH;

  const float *obj, *cls, *reg;
  int hw, w; float stride;
  if (lvl == 0)      { obj = obj8;  cls = cls8;  reg = reg8;  hw = 25600; w = 160; stride = 8.0f;  }
  else if (lvl == 1) { obj = obj16; cls = cls16; reg = reg16; hw = 6400;  w = 80;  stride = 16.0f; }
  else               { obj = obj32; cls = cls32; reg = reg32; hw = 1600;  w = 40;  stride = 32.0f; }
  obj += (size_t)img * hw;
  cls += (size_t)img * hw * NUM_CLASSES;
  reg += (size_t)img * hw * 4;

  if (threadIdx.x == 0) { cnt = 0; thrKey = 0ull; }
  __syncthreads();

  for (int base = 0; base < hw; base += TILE) {
    u64 thr = thrKey;
    int a = base + threadIdx.x;
    if (a < hw) {
      float so = 1.0f / (1.0f + expf(-obj[a]));
      #pragma unroll
      for (int c = 0; c < NUM_CLASSES; ++c) {
        float cv = cls[a * NUM_CLASSES + c];
        float sc = 1.0f / (1.0f + expf(-cv));
        float s  = sqrtf(__fmul_rn(so, sc));
        u64 key = ((u64)__float_as_uint(s) << 32) | (u32)(~(u32)(a * NUM_CLASSES + c));
        if (key > thr) {
          int p = atomicAdd(&cnt, 1);   // bounded by CAP via watermark invariant
          if (p < CAP) keys[p] = key;   // defensive clamp; never taken
        }
      }
    }
    __syncthreads();
    if (cnt > WATERMARK) {
      int n = cnt; if (n > CAP) n = CAP;
      int m = 64; while (m < n) m <<= 1;
      for (int i = n + threadIdx.x; i < m; i += blockDim.x) keys[i] = 0ull;
      bitonic_desc(keys, m);
      if (threadIdx.x == 0) { cnt = TOPK; thrKey = keys[TOPK - 1]; }
      __syncthreads();
    }
  }

  // Final sort of surviving candidates (cnt >= 64 always: first tile pushes all).
  {
    int n = cnt; if (n > CAP) n = CAP;
    int m = 64; while (m < n) m <<= 1;
    for (int i = n + threadIdx.x; i < m; i += blockDim.x) keys[i] = 0ull;
    bitonic_desc(keys, m);
  }

  if (threadIdx.x < TOPK) {
    u64 key = keys[threadIdx.x];
    float s = __uint_as_float((u32)(key >> 32));
    u32 idx = ~((u32)key);
    int a = (int)(idx / NUM_CLASSES);
    int c = (int)(idx - (u32)a * NUM_CLASSES);
    int ix = a % w, iy = a / w;
    // strides are powers of two: anchor math exact in f32, matching numpy
    float ax = __fmul_rn((float)ix + 0.5f, stride);
    float ay = __fmul_rn((float)iy + 0.5f, stride);
    float r0 = reg[a*4+0], r1 = reg[a*4+1], r2 = reg[a*4+2], r3 = reg[a*4+3];
    float cx = __fadd_rn(__fmul_rn(r0, stride), ax);
    float cy = __fadd_rn(__fmul_rn(r1, stride), ay);
    float wd = __fmul_rn(expf(r2), stride);
    float ht = __fmul_rn(expf(r3), stride);
    float x1 = __fsub_rn(cx, __fmul_rn(0.5f, wd));
    float y1 = __fsub_rn(cy, __fmul_rn(0.5f, ht));
    float x2 = __fadd_rn(cx, __fmul_rn(0.5f, wd));
    float y2 = __fadd_rn(cy, __fmul_rn(0.5f, ht));
    int p  = lvl * TOPK + threadIdx.x;
    int gi = img * TOTK + p;
    ws_score[gi] = s;
    ws_label[gi] = c;
    ws_box[gi*4+0] = x1; ws_box[gi*4+1] = y1;
    ws_box[gi*4+2] = x2; ws_box[gi*4+3] = y2;
  }
}

// One wave per image: stable sort of 192 entries by (score desc, pos asc),
// then wave-synchronous greedy class-offset NMS (no barriers in the i-loop).
__global__ __launch_bounds__(64) void nms_kernel(
    const float* __restrict__ ws_score, const int* __restrict__ ws_label,
    const float* __restrict__ ws_box, float* __restrict__ out) {
  __shared__ u64   skeys[256];
  __shared__ int   slb[TOTK];
  __shared__ float sbx[TOTK * 4];

  const int lane = threadIdx.x;
  const int img  = blockIdx.x;

  float lm = 0.0f;
  #pragma unroll
  for (int t = 0; t < 3; ++t) {
    int p  = lane + 64 * t;
    int gi = img * TOTK + p;
    float sc = ws_score[gi];
    int   lb = ws_label[gi];
    float b0 = ws_box[gi*4+0], b1 = ws_box[gi*4+1];
    float b2 = ws_box[gi*4+2], b3 = ws_box[gi*4+3];
    slb[p] = lb;
    sbx[p*4+0] = b0; sbx[p*4+1] = b1; sbx[p*4+2] = b2; sbx[p*4+3] = b3;
    skeys[p] = ((u64)__float_as_uint(sc) << 32) | (u32)(~(u32)p);
    lm = fmaxf(lm, fmaxf(fmaxf(fabsf(b0), fabsf(b1)), fmaxf(fabsf(b2), fabsf(b3))));
  }
  skeys[TOTK + lane] = 0ull;   // pad 192..255; real keys have score bits > 0
  #pragma unroll
  for (int d = 32; d > 0; d >>= 1) lm = fmaxf(lm, __shfl_xor(lm, d, 64));
  __syncthreads();
  bitonic_desc(skeys, 256);

  const float offscale = __fadd_rn(__fmul_rn(2.0f, lm), 1.0f);

  float sx1[3], sy1[3], sx2[3], sy2[3], area[3], scr[3];
  int pp[3], lbl[3];
  int keepmask = 0;
  #pragma unroll
  for (int t = 0; t < 3; ++t) {
    int r = lane + 64 * t;            // sorted rank, 0..191
    u64 key = skeys[r];
    int p = (int)(~((u32)key)) & 255;
    pp[t] = p;
    float sc = __uint_as_float((u32)(key >> 32));
    scr[t] = sc;
    int lb = slb[p]; lbl[t] = lb;
    float off = __fmul_rn((float)lb, offscale);
    float b0 = sbx[p*4+0], b1 = sbx[p*4+1], b2 = sbx[p*4+2], b3 = sbx[p*4+3];
    float X1 = __fadd_rn(b0, off), Y1 = __fadd_rn(b1, off);
    float X2 = __fadd_rn(b2, off), Y2 = __fadd_rn(b3, off);
    sx1[t] = X1; sy1[t] = Y1; sx2[t] = X2; sy2[t] = Y2;
    area[t] = __fmul_rn(__fsub_rn(X2, X1), __fsub_rn(Y2, Y1));
    if (sc > CONF_THRESH) keepmask |= (1 << t);
  }

  // Greedy NMS, wave-synchronous: lane (i&63), slot (i>>6) owns box i.
  for (int i = 0; i < TOTK; ++i) {
    int owner = i & 63, slot = i >> 6;
    int km = __shfl(keepmask, owner, 64);
    if (!((km >> slot) & 1)) continue;           // uniform across wave
    float bx1 = __shfl(SEL3(sx1, slot), owner, 64);
    float by1 = __shfl(SEL3(sy1, slot), owner, 64);
    float bx2 = __shfl(SEL3(sx2, slot), owner, 64);
    float by2 = __shfl(SEL3(sy2, slot), owner, 64);
    float ba  = __shfl(SEL3(area, slot), owner, 64);
    #pragma unroll
    for (int t = 0; t < 3; ++t) {
      int r = lane + 64 * t;
      if (r > i) {
        float xx1 = fmaxf(bx1, sx1[t]);
        float yy1 = fmaxf(by1, sy1[t]);
        float xx2 = fminf(bx2, sx2[t]);
        float yy2 = fminf(by2, sy2[t]);
        float wv = fmaxf(1e-10f, __fsub_rn(xx2, xx1));
        float hv = fmaxf(1e-10f, __fsub_rn(yy2, yy1));
        float inter = __fmul_rn(wv, hv);
        float denom = __fsub_rn(__fadd_rn(ba, area[t]), inter);
        float iou = __fdiv_rn(inter, denom);
        if (iou > NMS_THRESH) keepmask &= ~(1 << t);
      }
    }
  }

  float* out_boxes  = out;
  float* out_scores = out + (size_t)BATCH * TOTK * 4;
  float* out_labels = out + (size_t)BATCH * TOTK * 5;
  #pragma unroll
  for (int t = 0; t < 3; ++t) {
    int r  = lane + 64 * t;
    int gi = img * TOTK + r;
    bool kp = (keepmask >> t) & 1;
    int p = pp[t];
    out_boxes[gi*4+0] = kp ? sbx[p*4+0] : 0.0f;
    out_boxes[gi*4+1] = kp ? sbx[p*4+1] : 0.0f;
    out_boxes[gi*4+2] = kp ? sbx[p*4+2] : 0.0f;
    out_boxes[gi*4+3] = kp ? sbx[p*4+3] : 0.0f;
    out_scores[gi] = kp ? scr[t] : 0.0f;
    out_labels[gi] = kp ? (float)lbl[t] : -1.0f;
  }
}

extern "C" void kernel_launch(void* const* d_in, const int* in_sizes, int n_in,
                              void* d_out, int out_size, void* d_ws, size_t ws_size,
                              hipStream_t stream) {
  const float* obj8  = (const float*)d_in[0];
  const float* cls8  = (const float*)d_in[1];
  const float* reg8  = (const float*)d_in[2];
  const float* obj16 = (const float*)d_in[3];
  const float* cls16 = (const float*)d_in[4];
  const float* reg16 = (const float*)d_in[5];
  const float* obj32 = (const float*)d_in[6];
  const float* cls32 = (const float*)d_in[7];
  const float* reg32 = (const float*)d_in[8];

  float* ws_score = (float*)d_ws;
  int*   ws_label = (int*)  ((char*)d_ws + (size_t)BATCH * TOTK * sizeof(float));
  float* ws_box   = (float*)((char*)d_ws + (size_t)BATCH * TOTK * 2 * sizeof(float));

  topk_kernel<<<dim3(3 * BATCH), dim3(TILE), 0, stream>>>(
      obj8, cls8, reg8, obj16, cls16, reg16, obj32, cls32, reg32,
      ws_score, ws_label, ws_box);
  nms_kernel<<<dim3(BATCH), dim3(64), 0, stream>>>(
      ws_score, ws_label, ws_box, (float*)d_out);
}

// Round 3
// 312.453 us; speedup vs baseline: 1.4288x; 1.4288x over previous
//
#include <hip/hip_runtime.h>

// YOLO post-process, 3 kernels:
//  scan : per (img, level-chunk) exact streaming top-64 of anchor*class scores
//  merge: per (img, level) sort chunk top-64s -> level top-64, decode boxes
//  nms  : per img stable sort 192 + parallel IoU bit-matrix + greedy bit-sweep

#define NUM_CLASSES 5
#define CONF_THRESH 0.6f
#define NMS_THRESH  0.2f
#define TOPK   64
#define BATCH  128
#define TOTK   192
#define NCHUNK 11      // per image: 8 (lvl0, 3200 each) + 2 (lvl1, 3200) + 1 (lvl2, 1600)
#define SCAP   2048    // LDS candidate buffer (u64)
#define SOFT   512     // compact when cnt exceeds this; worst next-tile cnt = 512+1280 <= SCAP

typedef unsigned long long u64;
typedef unsigned int u32;

// Descending bitonic sort of k[0..m) (m pow2), block-cooperative.
// First action is a barrier (covers preceding LDS writes); ends with a barrier.
__device__ void bitonic_desc(u64* k, int m) {
  for (int kk = 2; kk <= m; kk <<= 1) {
    for (int j = kk >> 1; j > 0; j >>= 1) {
      __syncthreads();
      for (int i = threadIdx.x; i < m; i += blockDim.x) {
        int ixj = i ^ j;
        if (ixj > i) {
          u64 a = k[i], b = k[ixj];
          bool sw = ((i & kk) == 0) ? (a < b) : (a > b);
          if (sw) { k[i] = b; k[ixj] = a; }
        }
      }
    }
  }
  __syncthreads();
}

// score = sqrt(sigmoid(obj)*sigmoid(cls)); key = (score_bits<<32) | ~idx
// reproduces lax.top_k order (value desc, index asc). Exact formulas kept
// from R2 (absmax 0.0 vs numpy ref).
__device__ inline u64 score_key(float so, float cv, int idx) {
  float sc = 1.0f / (1.0f + expf(-cv));
  float s  = sqrtf(__fmul_rn(so, sc));
  return ((u64)__float_as_uint(s) << 32) | (u32)(~(u32)idx);
}

__global__ __launch_bounds__(256) void scan_kernel(
    const float* __restrict__ obj8,  const float* __restrict__ cls8,
    const float* __restrict__ obj16, const float* __restrict__ cls16,
    const float* __restrict__ obj32, const float* __restrict__ cls32,
    u64* __restrict__ ws_part) {
  __shared__ u64 keys[SCAP];
  __shared__ int cnt;
  __shared__ u64 thrKey;

  const int bx  = blockIdx.x;
  const int img = bx / NCHUNK;
  const int c   = bx - img * NCHUNK;
  const int tid = threadIdx.x;

  const float *obj, *cls;
  int hw, off, num;
  if (c < 8)       { obj = obj8;  cls = cls8;  hw = 25600; off = c * 3200;       num = 3200; }
  else if (c < 10) { obj = obj16; cls = cls16; hw = 6400;  off = (c - 8) * 3200; num = 3200; }
  else             { obj = obj32; cls = cls32; hw = 1600;  off = 0;              num = 1600; }
  obj += (size_t)img * hw;
  cls += (size_t)img * hw * NUM_CLASSES;

  // ---- seed tile: anchors off+tid (num >= 1600 > 256, all valid) ----
  u64 kk[NUM_CLASSES];
  {
    int ga = off + tid;
    float so = 1.0f / (1.0f + expf(-obj[ga]));
    #pragma unroll
    for (int c5 = 0; c5 < NUM_CLASSES; ++c5)
      kk[c5] = score_key(so, cls[ga * NUM_CLASSES + c5], ga * NUM_CLASSES + c5);
  }
  u64 mx = kk[0];
  #pragma unroll
  for (int c5 = 1; c5 < NUM_CLASSES; ++c5) if (kk[c5] > mx) mx = kk[c5];
  keys[tid] = mx;
  bitonic_desc(keys, 256);
  // 64th-largest of per-thread maxes: each max is a distinct real key, so
  // >=64 keys >= keys[63] -> conservative seed threshold. thrKey semantics:
  // push iff key > thrKey, so store seed-1 (keys have score bits>0 => >=2^32).
  u64 thr = keys[63] - 1ull;
  __syncthreads();                       // all threads read keys[63] first
  if (tid == 0) { cnt = 0; thrKey = thr; }
  __syncthreads();
  #pragma unroll
  for (int c5 = 0; c5 < NUM_CLASSES; ++c5)
    if (kk[c5] > thr) { int p = atomicAdd(&cnt, 1); if (p < SCAP) keys[p] = kk[c5]; }

  __syncthreads();
  int cs = cnt;
  __syncthreads();                       // snapshot fence: no push passes before all read
  if (cs > SOFT) {
    int m = 64; while (m < cs) m <<= 1;
    for (int i = cs + tid; i < m; i += 256) keys[i] = 0ull;
    bitonic_desc(keys, m);
    if (tid == 0) { cnt = TOPK; thrKey = keys[TOPK - 1]; }
    __syncthreads();
  }

  // ---- remaining tiles ----
  for (int base = 256; base < num; base += 256) {
    thr = thrKey;
    int a = base + tid;
    if (a < num) {
      int ga = off + a;
      float so = 1.0f / (1.0f + expf(-obj[ga]));
      #pragma unroll
      for (int c5 = 0; c5 < NUM_CLASSES; ++c5) {
        u64 key = score_key(so, cls[ga * NUM_CLASSES + c5], ga * NUM_CLASSES + c5);
        if (key > thr) { int p = atomicAdd(&cnt, 1); if (p < SCAP) keys[p] = key; }
      }
    }
    __syncthreads();
    cs = cnt;
    __syncthreads();
    if (cs > SOFT) {
      int m = 64; while (m < cs) m <<= 1;
      for (int i = cs + tid; i < m; i += 256) keys[i] = 0ull;
      bitonic_desc(keys, m);
      if (tid == 0) { cnt = TOPK; thrKey = keys[TOPK - 1]; }
      __syncthreads();
    }
  }

  // ---- final sort, emit chunk top-64 ----
  __syncthreads();
  cs = cnt;
  __syncthreads();
  {
    int m = 64; while (m < cs) m <<= 1;
    for (int i = cs + tid; i < m; i += 256) keys[i] = 0ull;
    bitonic_desc(keys, m);
  }
  if (tid < TOPK) ws_part[(size_t)bx * TOPK + tid] = keys[tid];
}

// One block per (img, level): sort nchunk*64 keys, keep 64, decode boxes.
__global__ __launch_bounds__(256) void merge_kernel(
    const u64* __restrict__ ws_part,
    const float* __restrict__ reg8, const float* __restrict__ reg16, const float* __restrict__ reg32,
    float* __restrict__ ws_score, int* __restrict__ ws_label, float* __restrict__ ws_box) {
  __shared__ u64 keys[512];
  const int bx  = blockIdx.x;
  const int img = bx / 3;
  const int lvl = bx - img * 3;
  const int tid = threadIdx.x;

  const float* reg; int nchunk, cbase, w, hw; float stride;
  if (lvl == 0)      { reg = reg8;  nchunk = 8; cbase = 0;  w = 160; hw = 25600; stride = 8.0f;  }
  else if (lvl == 1) { reg = reg16; nchunk = 2; cbase = 8;  w = 80;  hw = 6400;  stride = 16.0f; }
  else               { reg = reg32; nchunk = 1; cbase = 10; w = 40;  hw = 1600;  stride = 32.0f; }
  reg += (size_t)img * hw * 4;
  const int nk = nchunk * TOPK;                     // 512 / 128 / 64 (pow2)
  const u64* src = ws_part + ((size_t)img * NCHUNK + cbase) * TOPK;
  for (int i = tid; i < nk; i += 256) keys[i] = src[i];
  bitonic_desc(keys, nk);

  if (tid < TOPK) {
    u64 key = keys[tid];
    float s = __uint_as_float((u32)(key >> 32));
    u32 idx = ~((u32)key);
    int a = (int)(idx / NUM_CLASSES);
    int c = (int)(idx - (u32)a * NUM_CLASSES);
    int ix = a % w, iy = a / w;
    float ax = __fmul_rn((float)ix + 0.5f, stride);
    float ay = __fmul_rn((float)iy + 0.5f, stride);
    float r0 = reg[a*4+0], r1 = reg[a*4+1], r2 = reg[a*4+2], r3 = reg[a*4+3];
    float cx = __fadd_rn(__fmul_rn(r0, stride), ax);
    float cy = __fadd_rn(__fmul_rn(r1, stride), ay);
    float wd = __fmul_rn(expf(r2), stride);
    float ht = __fmul_rn(expf(r3), stride);
    float x1 = __fsub_rn(cx, __fmul_rn(0.5f, wd));
    float y1 = __fsub_rn(cy, __fmul_rn(0.5f, ht));
    float x2 = __fadd_rn(cx, __fmul_rn(0.5f, wd));
    float y2 = __fadd_rn(cy, __fmul_rn(0.5f, ht));
    int gi = img * TOTK + lvl * TOPK + tid;
    ws_score[gi] = s;
    ws_label[gi] = c;
    ws_box[gi*4+0] = x1; ws_box[gi*4+1] = y1;
    ws_box[gi*4+2] = x2; ws_box[gi*4+3] = y2;
  }
}

// One block (192 threads) per image.
__global__ __launch_bounds__(192) void nms_kernel(
    const float* __restrict__ ws_score, const int* __restrict__ ws_label,
    const float* __restrict__ ws_box, float* __restrict__ out) {
  __shared__ u64   skeys[256];
  __shared__ int   slb[TOTK];
  __shared__ float sbx[TOTK * 4];
  __shared__ float sX1[TOTK], sY1[TOTK], sX2[TOTK], sY2[TOTK], sA[TOTK];
  __shared__ u64   rows[TOTK * 3];
  __shared__ u64   svalid[3];
  __shared__ u64   skeep[3];
  __shared__ float lmarr[3];

  const int t   = threadIdx.x;
  const int img = blockIdx.x;

  // load + max|box| wave-reduce
  {
    int gi = img * TOTK + t;
    float sc = ws_score[gi];
    int   lb = ws_label[gi];
    float b0 = ws_box[gi*4+0], b1 = ws_box[gi*4+1];
    float b2 = ws_box[gi*4+2], b3 = ws_box[gi*4+3];
    slb[t] = lb;
    sbx[t*4+0] = b0; sbx[t*4+1] = b1; sbx[t*4+2] = b2; sbx[t*4+3] = b3;
    skeys[t] = ((u64)__float_as_uint(sc) << 32) | (u32)(~(u32)t);
    if (t < 64) skeys[TOTK + t] = 0ull;
    float lm = fmaxf(fmaxf(fabsf(b0), fabsf(b1)), fmaxf(fabsf(b2), fabsf(b3)));
    #pragma unroll
    for (int d = 32; d > 0; d >>= 1) lm = fmaxf(lm, __shfl_xor(lm, d, 64));
    if ((t & 63) == 0) lmarr[t >> 6] = lm;
  }
  bitonic_desc(skeys, 256);   // internal barriers fence all prior LDS writes

  const float lmAll = fmaxf(fmaxf(lmarr[0], lmarr[1]), lmarr[2]);
  const float offscale = __fadd_rn(__fmul_rn(2.0f, lmAll), 1.0f);

  // rank phase: thread t owns sorted rank t
  u64 key = skeys[t];
  int p = (int)(~((u32)key));           // original position 0..191
  float sc_r = __uint_as_float((u32)(key >> 32));
  int lb_r = slb[p];
  float off = __fmul_rn((float)lb_r, offscale);
  float X1 = __fadd_rn(sbx[p*4+0], off), Y1 = __fadd_rn(sbx[p*4+1], off);
  float X2 = __fadd_rn(sbx[p*4+2], off), Y2 = __fadd_rn(sbx[p*4+3], off);
  float A  = __fmul_rn(__fsub_rn(X2, X1), __fsub_rn(Y2, Y1));
  sX1[t] = X1; sY1[t] = Y1; sX2[t] = X2; sY2[t] = Y2; sA[t] = A;
  {
    u64 bal = __ballot(sc_r > CONF_THRESH);
    if ((t & 63) == 0) svalid[t >> 6] = bal;
  }
  __syncthreads();

  // suppression row t: bit j set iff iou(t,j) > thresh, j > t
  {
    u64 r0 = 0, r1 = 0, r2 = 0;
    for (int j = t + 1; j < TOTK; ++j) {
      float xx1 = fmaxf(X1, sX1[j]);
      float yy1 = fmaxf(Y1, sY1[j]);
      float xx2 = fminf(X2, sX2[j]);
      float yy2 = fminf(Y2, sY2[j]);
      float wv = fmaxf(1e-10f, __fsub_rn(xx2, xx1));
      float hv = fmaxf(1e-10f, __fsub_rn(yy2, yy1));
      float inter = __fmul_rn(wv, hv);
      float den = __fsub_rn(__fadd_rn(A, sA[j]), inter);
      float iou = __fdiv_rn(inter, den);
      if (iou > NMS_THRESH) {
        u64 b = 1ull << (j & 63);
        int wd = j >> 6;
        r0 |= (wd == 0) ? b : 0ull;
        r1 |= (wd == 1) ? b : 0ull;
        r2 |= (wd == 2) ? b : 0ull;
      }
    }
    rows[t*3+0] = r0; rows[t*3+1] = r1; rows[t*3+2] = r2;
  }
  __syncthreads();

  // greedy bit-sweep (wave 0, all lanes redundant; branchless, pipelineable)
  if (t < 64) {
    u64 k0 = svalid[0], k1 = svalid[1], k2 = svalid[2];
    #pragma unroll 4
    for (int i = 0; i < 64; ++i) {
      u64 m0 = rows[i*3+0], m1 = rows[i*3+1], m2 = rows[i*3+2];
      u64 sel = 0ull - ((k0 >> i) & 1ull);
      k0 &= ~(m0 & sel); k1 &= ~(m1 & sel); k2 &= ~(m2 & sel);
    }
    #pragma unroll 4
    for (int i = 0; i < 64; ++i) {
      int r = 64 + i;
      u64 m0 = rows[r*3+0], m1 = rows[r*3+1], m2 = rows[r*3+2];
      u64 sel = 0ull - ((k1 >> i) & 1ull);
      k0 &= ~(m0 & sel); k1 &= ~(m1 & sel); k2 &= ~(m2 & sel);
    }
    #pragma unroll 4
    for (int i = 0; i < 64; ++i) {
      int r = 128 + i;
      u64 m0 = rows[r*3+0], m1 = rows[r*3+1], m2 = rows[r*3+2];
      u64 sel = 0ull - ((k2 >> i) & 1ull);
      k0 &= ~(m0 & sel); k1 &= ~(m1 & sel); k2 &= ~(m2 & sel);
    }
    if (t == 0) { skeep[0] = k0; skeep[1] = k1; skeep[2] = k2; }
  }
  __syncthreads();

  // output
  float* out_boxes  = out;
  float* out_scores = out + (size_t)BATCH * TOTK * 4;
  float* out_labels = out + (size_t)BATCH * TOTK * 5;
  bool kp = (skeep[t >> 6] >> (t & 63)) & 1ull;
  int gi = img * TOTK + t;
  out_boxes[gi*4+0] = kp ? sbx[p*4+0] : 0.0f;
  out_boxes[gi*4+1] = kp ? sbx[p*4+1] : 0.0f;
  out_boxes[gi*4+2] = kp ? sbx[p*4+2] : 0.0f;
  out_boxes[gi*4+3] = kp ? sbx[p*4+3] : 0.0f;
  out_scores[gi] = kp ? sc_r : 0.0f;
  out_labels[gi] = kp ? (float)lb_r : -1.0f;
}

extern "C" void kernel_launch(void* const* d_in, const int* in_sizes, int n_in,
                              void* d_out, int out_size, void* d_ws, size_t ws_size,
                              hipStream_t stream) {
  const float* obj8  = (const float*)d_in[0];
  const float* cls8  = (const float*)d_in[1];
  const float* reg8  = (const float*)d_in[2];
  const float* obj16 = (const float*)d_in[3];
  const float* cls16 = (const float*)d_in[4];
  const float* reg16 = (const float*)d_in[5];
  const float* obj32 = (const float*)d_in[6];
  const float* cls32 = (const float*)d_in[7];
  const float* reg32 = (const float*)d_in[8];

  // ws layout: part (1408*64 u64 = 720896 B) | score | label | box
  u64*   ws_part  = (u64*)d_ws;
  char*  base     = (char*)d_ws + (size_t)BATCH * NCHUNK * TOPK * sizeof(u64);
  float* ws_score = (float*)base;
  int*   ws_label = (int*)(base + (size_t)BATCH * TOTK * sizeof(float));
  float* ws_box   = (float*)(base + (size_t)BATCH * TOTK * 2 * sizeof(float));

  scan_kernel<<<dim3(BATCH * NCHUNK), dim3(256), 0, stream>>>(
      obj8, cls8, obj16, cls16, obj32, cls32, ws_part);
  merge_kernel<<<dim3(BATCH * 3), dim3(256), 0, stream>>>(
      ws_part, reg8, reg16, reg32, ws_score, ws_label, ws_box);
  nms_kernel<<<dim3(BATCH), dim3(192), 0, stream>>>(
      ws_score, ws_label, ws_box, (float*)d_out);
}